// Round 6
// baseline (493.511 us; speedup 1.0000x reference)
//
#include <hip/hip_runtime.h>

#define DI __device__ __forceinline__

constexpr int AEV = 384;
constexpr int H1N = 160;
constexpr int H2N = 128;
constexpr int H3N = 96;
constexpr int NSP = 4;
constexpr int W1P = 200;   // W1 K-half LDS row stride (halfs): 100 words -> 2-way aliasing (free)
constexpr int W2P = 168;   // W2 LDS row stride
constexpr int W3P = 136;   // W3 LDS row stride
constexpr int W3OFF = H2N * W2P;            // 21504 halfs; W2+W3 = 34560 halfs = 69120 B

using half8  = __attribute__((ext_vector_type(8))) _Float16;
using half4v = __attribute__((ext_vector_type(4))) _Float16;
using f32x4  = __attribute__((ext_vector_type(4))) float;

// Pre-transposed fp16 weights, [species][neuron][k] (753 KB, L2-resident)
__device__ __align__(16) _Float16 g_w1[NSP * H1N * AEV];
__device__ __align__(16) _Float16 g_w2[NSP * H2N * H1N];
__device__ __align__(16) _Float16 g_w3[NSP * H3N * H2N];

DI float celu_f(float x) {   // celu(x,0.1) = max(x,0)+0.1*(exp(min(x,0)/0.1)-1)
  return fmaxf(x, 0.f) + 0.1f * (exp2f(fminf(x, 0.f) * 14.426950408889634f) - 1.f);
}
DI f32x4 mfma16h(half8 a, half8 b, f32x4 c) {
  return __builtin_amdgcn_mfma_f32_16x16x32_f16(a, b, c, 0, 0, 0);
}
DI half8 cvt8(float4 a, float4 b) {
  half8 t;
  t[0] = (_Float16)a.x; t[1] = (_Float16)a.y; t[2] = (_Float16)a.z; t[3] = (_Float16)a.w;
  t[4] = (_Float16)b.x; t[5] = (_Float16)b.y; t[6] = (_Float16)b.z; t[7] = (_Float16)b.w;
  return t;
}
DI half4v shfl4(half4v v, int src) {
  union { half4v h; int i[2]; } u;
  u.h = v;
  u.i[0] = __shfl(u.i[0], src, 64);
  u.i[1] = __shfl(u.i[1], src, 64);
  return u.h;
}
// Build B-fragment slab ks from C-layout regs hb[] (one 16-atom tile):
// dest lane (l15=atom, quad) needs H[k=ks*32+quad*8+j][atom], living in
// hb[2ks+(quad>>1)] of lanes ((quad&1)*32 + l15) [lo] and (+16) [hi].
DI half8 bfrag(const half4v* hb, int ks, int l15, int quad) {
  const int sLo = (quad & 1) * 32 + l15, sHi = sLo + 16;
  half4v loA = shfl4(hb[2 * ks], sLo),     loB = shfl4(hb[2 * ks + 1], sLo);
  half4v hiA = shfl4(hb[2 * ks], sHi),     hiB = shfl4(hb[2 * ks + 1], sHi);
  half4v lo = (quad & 2) ? loB : loA;
  half4v hi = (quad & 2) ? hiB : hiA;
  half8 b;
  b[0] = lo[0]; b[1] = lo[1]; b[2] = lo[2]; b[3] = lo[3];
  b[4] = hi[0]; b[5] = hi[1]; b[6] = hi[2]; b[7] = hi[3];
  return b;
}

// ---------------- prologue: transpose to [s][n][k] fp16, fused for 3 layers ----
template <int K, int N>
DI void tp(const float* __restrict__ src, _Float16* dst, int id) {
  constexpr int per = K * N;
  int s = id / per, r = id % per;
  int n = r / K, k = r % K;
  dst[s * per + n * K + k] = (_Float16)src[s * per + k * N + n];
}

__global__ void prep(const float* __restrict__ W1, const float* __restrict__ W2,
                     const float* __restrict__ W3, float* __restrict__ out) {
  int id = blockIdx.x * 256 + threadIdx.x;
  if (id == 0) out[0] = 0.f;
  constexpr int E1 = NSP * AEV * H1N;
  constexpr int E2 = NSP * H1N * H2N;
  constexpr int E3 = NSP * H2N * H3N;
  if (id < E1)                 tp<AEV, H1N>(W1, g_w1, id);
  else if (id < E1 + E2)       tp<H1N, H2N>(W2, g_w2, id - E1);
  else if (id < E1 + E2 + E3)  tp<H2N, H3N>(W3, g_w3, id - E1 - E2);
}

// ---- fused MLP: 32 atoms/wave (2 B-tiles per A-read), LDS = weights only ----
__global__ __launch_bounds__(256, 2) void fused_mlp(
    const float* __restrict__ aev,
    const float* __restrict__ b1, const float* __restrict__ b2,
    const float* __restrict__ b3,
    const float* __restrict__ W4, const float* __restrict__ pb4,
    const int* __restrict__ i0, const int* __restrict__ i1,
    const int* __restrict__ i2, const int* __restrict__ i3,
    int chunk, float* __restrict__ out) {
  __shared__ __align__(16) _Float16 WS[34560];   // 69120 B: W1-half | later W2+W3
  __shared__ float RED[4];

  const int tid  = threadIdx.x;
  const int lane = tid & 63, wav = tid >> 6;
  const int l15  = lane & 15, quad = lane >> 4;
  const int s    = blockIdx.y;
  const int* idx = (s == 0) ? i0 : (s == 1) ? i1 : (s == 2) ? i2 : i3;

  const int a0 = blockIdx.x * 128 + wav * 32 + l15;    // species-local atoms
  const int a1 = a0 + 16;
  const bool v0 = (a0 < chunk), v1 = (a1 < chunk);
  const int r0 = idx[v0 ? a0 : (chunk - 1)];
  const int r1 = idx[v1 ? a1 : (chunk - 1)];
  const float* xr0 = aev + (size_t)r0 * AEV + quad * 8;
  const float* xr1 = aev + (size_t)r1 * AEV + quad * 8;
  const float  b4s = pb4[s];

  const _Float16* w1src = g_w1 + (size_t)s * H1N * AEV;

  // ---- stage W1 K-half 0 (k=0..191), stride W1P: 160*24 = 3840 = 15*256 chunks
#pragma unroll
  for (int i = 0; i < 15; ++i) {
    int c = tid + i * 256;
    int n = c / 24, kc = c % 24;
    *(half8*)(WS + n * W1P + kc * 8) = *(const half8*)(w1src + n * AEV + kc * 8);
  }
  __syncthreads();

  // ---- Layer 1 (K=384 split 2x192)
  f32x4 acc[10][2];
#pragma unroll
  for (int m = 0; m < 10; ++m)
#pragma unroll
    for (int nt = 0; nt < 2; ++nt)
#pragma unroll
      for (int i = 0; i < 4; ++i) acc[m][nt][i] = 0.f;

  float4 p00 = *(const float4*)(xr0), p01 = *(const float4*)(xr0 + 4);
  float4 p10 = *(const float4*)(xr1), p11 = *(const float4*)(xr1 + 4);
#pragma unroll
  for (int ks = 0; ks < 6; ++ks) {
    half8 bv0 = cvt8(p00, p01), bv1 = cvt8(p10, p11);
    p00 = *(const float4*)(xr0 + (ks + 1) * 32);   // ks=5 pulls half-1's first slab
    p01 = *(const float4*)(xr0 + (ks + 1) * 32 + 4);
    p10 = *(const float4*)(xr1 + (ks + 1) * 32);
    p11 = *(const float4*)(xr1 + (ks + 1) * 32 + 4);
#pragma unroll
    for (int mt = 0; mt < 10; ++mt) {
      half8 aw = *(const half8*)(WS + (mt * 16 + l15) * W1P + ks * 32 + quad * 8);
      acc[mt][0] = mfma16h(aw, bv0, acc[mt][0]);
      acc[mt][1] = mfma16h(aw, bv1, acc[mt][1]);
    }
  }
  __syncthreads();                                 // done reading half 0
#pragma unroll
  for (int i = 0; i < 15; ++i) {                   // stage K-half 1 (k=192..383)
    int c = tid + i * 256;
    int n = c / 24, kc = c % 24;
    *(half8*)(WS + n * W1P + kc * 8) = *(const half8*)(w1src + 192 + n * AEV + kc * 8);
  }
  __syncthreads();
#pragma unroll
  for (int ks = 6; ks < 12; ++ks) {
    half8 bv0 = cvt8(p00, p01), bv1 = cvt8(p10, p11);
    if (ks < 11) {
      p00 = *(const float4*)(xr0 + (ks + 1) * 32);
      p01 = *(const float4*)(xr0 + (ks + 1) * 32 + 4);
      p10 = *(const float4*)(xr1 + (ks + 1) * 32);
      p11 = *(const float4*)(xr1 + (ks + 1) * 32 + 4);
    }
#pragma unroll
    for (int mt = 0; mt < 10; ++mt) {
      half8 aw = *(const half8*)(WS + (mt * 16 + l15) * W1P + (ks - 6) * 32 + quad * 8);
      acc[mt][0] = mfma16h(aw, bv0, acc[mt][0]);
      acc[mt][1] = mfma16h(aw, bv1, acc[mt][1]);
    }
  }
  // epilogue in regs: hb[nt][mt][i] = H1[n=mt*16+quad*4+i][atom tile nt, col l15]
  half4v hb[2][10];
#pragma unroll
  for (int mt = 0; mt < 10; ++mt) {
    float4 bb = *(const float4*)(b1 + s * H1N + mt * 16 + quad * 4);
#pragma unroll
    for (int nt = 0; nt < 2; ++nt) {
      half4v o;
      o[0] = (_Float16)celu_f(acc[mt][nt][0] + bb.x);
      o[1] = (_Float16)celu_f(acc[mt][nt][1] + bb.y);
      o[2] = (_Float16)celu_f(acc[mt][nt][2] + bb.z);
      o[3] = (_Float16)celu_f(acc[mt][nt][3] + bb.w);
      hb[nt][mt] = o;
    }
  }

  __syncthreads();                                 // done reading W1 half 1
  {                                                // stage W2 + W3
    const _Float16* w2src = g_w2 + (size_t)s * H2N * H1N;
    const _Float16* w3src = g_w3 + (size_t)s * H3N * H2N;
#pragma unroll
    for (int i = 0; i < 10; ++i) {
      int c = tid + i * 256;                       // 128*20 = 2560 exact
      int n = c / 20, kc = c % 20;
      *(half8*)(WS + n * W2P + kc * 8) = *(const half8*)(w2src + n * H1N + kc * 8);
    }
#pragma unroll
    for (int i = 0; i < 6; ++i) {
      int c = tid + i * 256;                       // 96*16 = 1536 exact
      int n = c / 16, kc = c % 16;
      *(half8*)(WS + W3OFF + n * W3P + kc * 8) = *(const half8*)(w3src + n * H2N + kc * 8);
    }
  }
  __syncthreads();

  // ---- Layer 2 (K=160)
  f32x4 acc2[8][2];
#pragma unroll
  for (int m = 0; m < 8; ++m)
#pragma unroll
    for (int nt = 0; nt < 2; ++nt)
#pragma unroll
      for (int i = 0; i < 4; ++i) acc2[m][nt][i] = 0.f;
#pragma unroll
  for (int ks = 0; ks < 5; ++ks) {
    half8 bv0 = bfrag(hb[0], ks, l15, quad);
    half8 bv1 = bfrag(hb[1], ks, l15, quad);
#pragma unroll
    for (int mt = 0; mt < 8; ++mt) {
      half8 aw = *(const half8*)(WS + (mt * 16 + l15) * W2P + ks * 32 + quad * 8);
      acc2[mt][0] = mfma16h(aw, bv0, acc2[mt][0]);
      acc2[mt][1] = mfma16h(aw, bv1, acc2[mt][1]);
    }
  }
  half4v hb2[2][8];
#pragma unroll
  for (int mt = 0; mt < 8; ++mt) {
    float4 bb = *(const float4*)(b2 + s * H2N + mt * 16 + quad * 4);
#pragma unroll
    for (int nt = 0; nt < 2; ++nt) {
      half4v o;
      o[0] = (_Float16)celu_f(acc2[mt][nt][0] + bb.x);
      o[1] = (_Float16)celu_f(acc2[mt][nt][1] + bb.y);
      o[2] = (_Float16)celu_f(acc2[mt][nt][2] + bb.z);
      o[3] = (_Float16)celu_f(acc2[mt][nt][3] + bb.w);
      hb2[nt][mt] = o;
    }
  }

  // ---- Layer 3 (K=128)
  f32x4 acc3[6][2];
#pragma unroll
  for (int m = 0; m < 6; ++m)
#pragma unroll
    for (int nt = 0; nt < 2; ++nt)
#pragma unroll
      for (int i = 0; i < 4; ++i) acc3[m][nt][i] = 0.f;
#pragma unroll
  for (int ks = 0; ks < 4; ++ks) {
    half8 bv0 = bfrag(hb2[0], ks, l15, quad);
    half8 bv1 = bfrag(hb2[1], ks, l15, quad);
#pragma unroll
    for (int mt = 0; mt < 6; ++mt) {
      half8 aw = *(const half8*)(WS + W3OFF + (mt * 16 + l15) * W3P + ks * 32 + quad * 8);
      acc3[mt][0] = mfma16h(aw, bv0, acc3[mt][0]);
      acc3[mt][1] = mfma16h(aw, bv1, acc3[mt][1]);
    }
  }

  // ---- Layer 4: per-lane partial dots over its (quad,i) neurons, both tiles
  float e0 = 0.f, e1 = 0.f;
#pragma unroll
  for (int mt = 0; mt < 6; ++mt) {
    float4 bb = *(const float4*)(b3 + s * H3N + mt * 16 + quad * 4);
    float4 wv = *(const float4*)(W4 + s * H3N + mt * 16 + quad * 4);
    e0 += (float)(_Float16)celu_f(acc3[mt][0][0] + bb.x) * wv.x
        + (float)(_Float16)celu_f(acc3[mt][0][1] + bb.y) * wv.y
        + (float)(_Float16)celu_f(acc3[mt][0][2] + bb.z) * wv.z
        + (float)(_Float16)celu_f(acc3[mt][0][3] + bb.w) * wv.w;
    e1 += (float)(_Float16)celu_f(acc3[mt][1][0] + bb.x) * wv.x
        + (float)(_Float16)celu_f(acc3[mt][1][1] + bb.y) * wv.y
        + (float)(_Float16)celu_f(acc3[mt][1][2] + bb.z) * wv.z
        + (float)(_Float16)celu_f(acc3[mt][1][3] + bb.w) * wv.w;
  }
  e0 += __shfl_xor(e0, 16, 64); e0 += __shfl_xor(e0, 32, 64);   // uniform per l15
  e1 += __shfl_xor(e1, 16, 64); e1 += __shfl_xor(e1, 32, 64);
  float tot = (v0 ? e0 + b4s : 0.f) + (v1 ? e1 + b4s : 0.f);
  if (lane >= 16) tot = 0.f;
#pragma unroll
  for (int off = 1; off < 16; off <<= 1) tot += __shfl_xor(tot, off, 64);
  if (lane == 0) RED[wav] = tot;
  __syncthreads();
  if (tid == 0) atomicAdd(out, RED[0] + RED[1] + RED[2] + RED[3]);
}

extern "C" void kernel_launch(void* const* d_in, const int* in_sizes, int n_in,
                              void* d_out, int out_size, void* d_ws, size_t ws_size,
                              hipStream_t stream) {
  (void)n_in; (void)d_ws; (void)ws_size; (void)out_size;
  const float* aev = (const float*)d_in[0];
  const float* W1  = (const float*)d_in[1];
  const float* b1  = (const float*)d_in[2];
  const float* W2  = (const float*)d_in[3];
  const float* b2  = (const float*)d_in[4];
  const float* W3  = (const float*)d_in[5];
  const float* b3  = (const float*)d_in[6];
  const float* W4  = (const float*)d_in[7];
  const float* b4  = (const float*)d_in[8];
  const int* iH = (const int*)d_in[9];
  const int* iC = (const int*)d_in[10];
  const int* iN = (const int*)d_in[11];
  const int* iO = (const int*)d_in[12];
  const int chunk = in_sizes[9];

  constexpr int TOT = NSP * (AEV * H1N + H1N * H2N + H2N * H3N);  // 376832 = 1472*256
  prep<<<TOT / 256, 256, 0, stream>>>(W1, W2, W3, (float*)d_out);

  const int tiles = (chunk + 127) / 128;
  fused_mlp<<<dim3(tiles, NSP), 256, 0, stream>>>(aev, b1, b2, b3, W4, b4,
                                                  iH, iC, iN, iO, chunk, (float*)d_out);
}